// Round 5
// baseline (337.209 us; speedup 1.0000x reference)
//
#include <hip/hip_runtime.h>

#define NN 51
#define NR 52     // padded node count (gumbel buffers)
#define NRV 56    // V rows / u cols padded to 56 (PV reads n in [0,56))
#define DD 128
#define RS 132    // LDS row stride (words)
#define NT 64

// JAX threefry2x32 (20 rounds), exact.
__device__ __forceinline__ void tf2x32(unsigned k0, unsigned k1, unsigned &x0, unsigned &x1) {
  const unsigned ks2 = k0 ^ k1 ^ 0x1BD11BDAu;
  const unsigned ka[5] = {k1, ks2, k0, k1, ks2};
  const unsigned kb[5] = {ks2 + 1u, k0 + 2u, k1 + 3u, ks2 + 4u, k0 + 5u};
  x0 += k0; x1 += k1;
#pragma unroll
  for (int g = 0; g < 5; ++g) {
    const int r0 = (g & 1) ? 17 : 13;
    const int r1 = (g & 1) ? 29 : 15;
    const int r2 = (g & 1) ? 16 : 26;
    const int r3 = (g & 1) ? 24 : 6;
    x0 += x1; x1 = (x1 << r0) | (x1 >> (32 - r0)); x1 ^= x0;
    x0 += x1; x1 = (x1 << r1) | (x1 >> (32 - r1)); x1 ^= x0;
    x0 += x1; x1 = (x1 << r2) | (x1 >> (32 - r2)); x1 ^= x0;
    x0 += x1; x1 = (x1 << r3) | (x1 >> (32 - r3)); x1 ^= x0;
    x0 += ka[g]; x1 += kb[g];
  }
}

__device__ __forceinline__ float gumbel_from(unsigned k0, unsigned k1, unsigned ctr) {
  unsigned x0 = 0u, x1 = ctr;
  tf2x32(k0, k1, x0, x1);
  const unsigned bits = x0 ^ x1;
  const float fl = __uint_as_float((bits >> 9) | 0x3f800000u) - 1.0f;
  const float TINY = 1.17549435e-38f;
  const float uu = fmaxf(TINY, fl + TINY);
  return -logf(-logf(uu));
}

__device__ __forceinline__ float dot4(const float4 a, const float4 b) {
  return a.x * b.x + a.y * b.y + a.z * b.z + a.w * b.w;
}

__global__ __launch_bounds__(256, 1) void decode_kernel(
    const float* __restrict__ enc, const float* __restrict__ pool_in,
    const float* __restrict__ cap_p, const float* __restrict__ demand,
    const float* __restrict__ fc_w, const float* __restrict__ fc1,
    const float* __restrict__ wq, const float* __restrict__ wk,
    const float* __restrict__ wv, const float* __restrict__ wo,
    const float* __restrict__ wkp, const float* __restrict__ T_p,
    const int* __restrict__ ns_p, const int* __restrict__ greedy_p,
    float* __restrict__ out) {
  __shared__ __align__(16) float Ksh[NN * RS];
  __shared__ __align__(16) float Vsh[NRV * RS];    // rows 51..55 zeroed
  __shared__ __align__(16) float KP2sh[NN * RS];   // T2=E@wkp -> KP2=T2@wo^T
  __shared__ __align__(16) float EQsh[NN * RS];    // T1=E@fc_top -> EQ=T1@wq
  __shared__ __align__(16) float qpoolL[NT * DD];  // first: staged enc; later qpool[t]
  __shared__ __align__(16) float uL[8 * NRV];      // attn weights, cols 51..55 zeroed
  __shared__ __align__(16) float qL[DD];
  __shared__ __align__(16) float gL[DD];
  __shared__ __align__(16) float poolL[DD];
  __shared__ __align__(16) float wrowL[DD];
  __shared__ __align__(16) float partF[256];
  __shared__ __align__(16) float partQ[256];
  __shared__ float maskL[NN], demL[NN];
  __shared__ float pgumL[2][NR];
  __shared__ unsigned keysL[2 * NT];

  const int b = blockIdx.x, tid = threadIdx.x;
  const int Bn = gridDim.x;
  int ns = *ns_p; if (ns > NT) ns = NT;
  const int greedy = *greedy_p;
  const float Tval = *T_p;
  const float cap0 = *cap_p;
  const float NINF = -__builtin_inff();

  // ---- stage: enc row (float4), demand, pool, threefry keys, zero pads ----
  {
    const float4* src = (const float4*)(enc + (size_t)b * NN * DD);
    float4* dst = (float4*)qpoolL;
    for (int e = tid; e < NN * DD / 4; e += 256) dst[e] = src[e];
  }
  if (tid < 128) poolL[tid] = pool_in[b * DD + tid];
  for (int e = tid; e < 5 * RS; e += 256) Vsh[51 * RS + e] = 0.f;  // rows 51..55
  if (tid < 32) uL[(tid >> 2) * NRV + 52 + (tid & 3)] = 0.f;       // cols 52..55
  if (tid < NN)  demL[tid] = demand[b * NN + tid];
  if (tid < ns) {  // fold_in(key(1234),0) then partitionable split child t
    unsigned a0 = 0u, a1 = 0u;
    tf2x32(0u, 1234u, a0, a1);
    unsigned x0 = 0u, x1 = (unsigned)tid;
    tf2x32(a0, a1, x0, x1);
    keysL[2 * tid] = x0; keysL[2 * tid + 1] = x1;
  }
  __syncthreads();

  const int g = tid >> 7, cc = tid & 127;
  const int n0 = g ? 26 : 0, cnt26 = g ? 25 : 26;

  // initial mask (idx=0, dyn=cap0, nothing visited)
  if (tid < NN)
    maskL[tid] = (tid == 0) ? 1.f : ((demL[tid] > cap0) ? 1.f : 0.f);
  // wrow[c] = fc_w[128,:] @ wq[:,c]
  if (tid < 128) {
    float s0 = 0.f, s1 = 0.f;
    for (int j = 0; j < DD; j += 2) {
      s0 += fc_w[128 * DD + j] * wq[j * DD + tid];
      s1 += fc_w[128 * DD + j + 1] * wq[(j + 1) * DD + tid];
    }
    wrowL[tid] = s0 + s1;
  }

  // ---- phase A: K=E@wk, V=E@wv, T1=E@fc_top, T2=E@wkp ----
  {
    const float* Wm[4] = {wk, wv, fc_w, wkp};
    float* Om[4] = {Ksh, Vsh, EQsh, KP2sh};
#pragma unroll
    for (int m = 0; m < 4; ++m) {
      const float* W = Wm[m];
      float acc[26];
#pragma unroll
      for (int r = 0; r < 26; ++r) acc[r] = 0.f;
      for (int i = 0; i < DD; i += 4) {
        const float w0 = W[(i + 0) * DD + cc];
        const float w1 = W[(i + 1) * DD + cc];
        const float w2 = W[(i + 2) * DD + cc];
        const float w3 = W[(i + 3) * DD + cc];
#pragma unroll
        for (int r = 0; r < 26; ++r) {
          if (r < cnt26) {
            const float4 e4 = *(const float4*)&qpoolL[(n0 + r) * DD + i];
            acc[r] += e4.x * w0 + e4.y * w1 + e4.z * w2 + e4.w * w3;
          }
        }
      }
      float* O = Om[m];
#pragma unroll
      for (int r = 0; r < 26; ++r) if (r < cnt26) O[(n0 + r) * RS + cc] = acc[r];
    }
  }
  __syncthreads();

  // ---- phase B1: EQ = T1 @ wq, in place ----
  {
    float acc[26];
#pragma unroll
    for (int r = 0; r < 26; ++r) acc[r] = 0.f;
    for (int i = 0; i < DD; i += 4) {
      const float w0 = wq[(i + 0) * DD + cc];
      const float w1 = wq[(i + 1) * DD + cc];
      const float w2 = wq[(i + 2) * DD + cc];
      const float w3 = wq[(i + 3) * DD + cc];
#pragma unroll
      for (int r = 0; r < 26; ++r) {
        if (r < cnt26) {
          const float4 e4 = *(const float4*)&EQsh[(n0 + r) * RS + i];
          acc[r] += e4.x * w0 + e4.y * w1 + e4.z * w2 + e4.w * w3;
        }
      }
    }
    __syncthreads();
#pragma unroll
    for (int r = 0; r < 26; ++r) if (r < cnt26) EQsh[(n0 + r) * RS + cc] = acc[r];
  }
  __syncthreads();

  // ---- phase B2: KP2 = T2 @ wo^T, in place ----
  {
    float acc[26];
#pragma unroll
    for (int r = 0; r < 26; ++r) acc[r] = 0.f;
    for (int d = 0; d < DD; d += 4) {
      const float4 w4 = *(const float4*)&wo[cc * DD + d];
#pragma unroll
      for (int r = 0; r < 26; ++r) {
        if (r < cnt26) {
          const float4 t4 = *(const float4*)&KP2sh[(n0 + r) * RS + d];
          acc[r] += t4.x * w4.x + t4.y * w4.y + t4.z * w4.z + t4.w * w4.w;
        }
      }
    }
    __syncthreads();
#pragma unroll
    for (int r = 0; r < 26; ++r) if (r < cnt26) KP2sh[(n0 + r) * RS + cc] = acc[r];
  }
  __syncthreads();

  // ---- phase C: pool chain; qpool[t] = pool_{t+1} @ wq ----
  {
    const int i0 = g << 6;
    float wf[64], wqr[64];
#pragma unroll
    for (int i = 0; i < 64; ++i) {
      wf[i]  = fc1[(i0 + i) * DD + cc];
      wqr[i] = wq[(i0 + i) * DD + cc];
    }
    float sf = 0.f;
#pragma unroll
    for (int i = 0; i < 64; ++i) sf += poolL[i0 + i] * wf[i];
    partF[tid] = sf;
    __syncthreads();
    if (tid < 128) poolL[tid] = partF[tid] + partF[tid + 128];  // pool_1
    __syncthreads();
    for (int t = 0; t < ns; ++t) {
      float sq = 0.f, sfn = 0.f;
#pragma unroll
      for (int i = 0; i < 64; ++i) {
        const float p = poolL[i0 + i];
        sq  += p * wqr[i];
        sfn += p * wf[i];
      }
      partQ[tid] = sq; partF[tid] = sfn;
      __syncthreads();
      if (tid < 128) {
        qpoolL[t * DD + tid] = partQ[tid] + partQ[tid + 128];
        if (t + 1 < ns) poolL[tid] = partF[tid] + partF[tid + 128];
      }
      __syncthreads();
    }
  }

  // ---- pre-loop: q(0), wave0 register state, gumbel(0) reg + gumbel(1) LDS ----
  float pg = 0.f, dem_l = 0.f, mask_l = 0.f, dynr = cap0, lpacc = 0.f;
  float wr0 = 0.f, wr1 = 0.f;
  int m1 = 0;
  {
    const int w = tid >> 6, l = tid & 63;
    if (tid < 128)
      qL[tid] = EQsh[tid] + cap0 * wrowL[tid] + qpoolL[tid];  // idx=0
    if (w == 0) {
      if (l < NN) dem_l = demL[l];
      mask_l = (l == 0) ? 1.f : ((l < NN) ? ((dem_l > cap0) ? 1.f : 0.f) : 0.f);
      wr0 = wrowL[l]; wr1 = wrowL[l + 64];
      if (!greedy && l < NN)
        pg = gumbel_from(keysL[0], keysL[1], (unsigned)(b * NN + l));
    }
    if (w == 3 && !greedy && ns > 1 && l < NN)
      pgumL[1][l] = gumbel_from(keysL[2], keysL[3], (unsigned)(b * NN + l));
  }
  __syncthreads();

  // ---- sequential decode: 2 barriers/step ----
  for (int t = 0; t < ns; ++t) {
    // X: attention (all 4 waves; wave w owns heads 2w, 2w+1)
    {
      const int w = tid >> 6, l = tid & 63;
      const int h = 2 * w + (l >> 5), j = l & 31;
      const float4* qr = (const float4*)&qL[h * 16];
      const float4 q0 = qr[0], q1 = qr[1], q2 = qr[2], q3 = qr[3];
      float u1, u2 = NINF;
      {
        const float4* kr = (const float4*)&Ksh[j * RS + h * 16];
        const float s = (dot4(kr[0], q0) + dot4(kr[1], q1)) +
                        (dot4(kr[2], q2) + dot4(kr[3], q3));
        u1 = (maskL[j] > 0.f) ? NINF : 0.25f * s;
      }
      if (j < 19) {
        const float4* kr = (const float4*)&Ksh[(j + 32) * RS + h * 16];
        const float s = (dot4(kr[0], q0) + dot4(kr[1], q1)) +
                        (dot4(kr[2], q2) + dot4(kr[3], q3));
        u2 = (maskL[j + 32] > 0.f) ? NINF : 0.25f * s;
      }
      float m = fmaxf(u1, u2);
#pragma unroll
      for (int o = 16; o; o >>= 1) m = fmaxf(m, __shfl_xor(m, o, 32));
      const float e1 = expf(u1 - m);
      const float e2 = (j < 19) ? expf(u2 - m) : 0.f;
      float ssum = e1 + e2;
#pragma unroll
      for (int o = 16; o; o >>= 1) ssum += __shfl_xor(ssum, o, 32);
      uL[h * NRV + j] = e1 / ssum;
      if (j < 19) uL[h * NRV + j + 32] = e2 / ssum;
      if (j == 19) uL[h * NRV + 51] = 0.f;
      asm volatile("s_waitcnt lgkmcnt(0)" ::: "memory");
      __builtin_amdgcn_sched_barrier(0);
      // PV: lane k of head-half -> quad qd (4 dims), node residue sres (mod 8)
      const int k = l & 31;
      const int qd = k & 3, sres = k >> 2;
      float4 acc = {0.f, 0.f, 0.f, 0.f};
#pragma unroll
      for (int jj = 0; jj < 7; ++jj) {
        const int n = 8 * jj + sres;
        const float a = uL[h * NRV + n];
        const float4 v4 = *(const float4*)&Vsh[n * RS + h * 16 + qd * 4];
        acc.x += a * v4.x; acc.y += a * v4.y; acc.z += a * v4.z; acc.w += a * v4.w;
      }
      acc.x += __shfl_xor(acc.x, 4);  acc.y += __shfl_xor(acc.y, 4);
      acc.z += __shfl_xor(acc.z, 4);  acc.w += __shfl_xor(acc.w, 4);
      acc.x += __shfl_xor(acc.x, 8);  acc.y += __shfl_xor(acc.y, 8);
      acc.z += __shfl_xor(acc.z, 8);  acc.w += __shfl_xor(acc.w, 8);
      acc.x += __shfl_xor(acc.x, 16); acc.y += __shfl_xor(acc.y, 16);
      acc.z += __shfl_xor(acc.z, 16); acc.w += __shfl_xor(acc.w, 16);
      if (sres == 0) *(float4*)&gL[h * 16 + qd * 4] = acc;
    }
    __syncthreads();
    // Y: wave0 = comp+logits+sample+state+next-q ; wave3 = gumbel(t+2)
    {
      const int w = tid >> 6, l = tid & 63;
      if (w == 0) {
        const float qp0 = qpoolL[(t + 1) * DD + l];
        const float qp1 = qpoolL[(t + 1) * DD + l + 64];
        float pgn = 0.f;
        if (!greedy && l < NN && t + 1 < ns) pgn = pgumL[(t + 1) & 1][l];
        float lgv = NINF;
        if (l < NN) {
          const float4* kp = (const float4*)&KP2sh[l * RS];
          const float4* gg = (const float4*)gL;
          float a0 = 0.f, a1 = 0.f, a2 = 0.f, a3 = 0.f;
#pragma unroll
          for (int i = 0; i < 32; i += 4) {
            a0 += dot4(kp[i],     gg[i]);
            a1 += dot4(kp[i + 1], gg[i + 1]);
            a2 += dot4(kp[i + 2], gg[i + 2]);
            a3 += dot4(kp[i + 3], gg[i + 3]);
          }
          const float comp = ((a0 + a1) + (a2 + a3)) * 0.08838834764831845f;
          const float lg = (10.f * tanhf(comp)) / Tval;
          lgv = (mask_l > 0.f) ? NINF : lg;
        }
        float v = (l < NN) ? (lgv + pg) : NINF;
        int bi = l;
        float mm = lgv;
#pragma unroll
        for (int o = 32; o; o >>= 1) {
          const float v2 = __shfl_xor(v, o);
          const int i2 = __shfl_xor(bi, o);
          const float m2 = __shfl_xor(mm, o);
          mm = fmaxf(mm, m2);
          if (v2 > v || (v2 == v && i2 < bi)) { v = v2; bi = i2; }
        }
        float ee = expf(lgv - mm);
#pragma unroll
        for (int o = 32; o; o >>= 1) ee += __shfl_xor(ee, o);
        const int best = bi;
        if (l == best) m1 = 1;
        const unsigned long long M = __ballot(m1 != 0);
        const int cntv = (int)__popcll(M & ~1ULL);
        const float dem_b = __shfl(dem_l, best);
        dynr = (best == 0) ? cap0 : (dynr - dem_b);
        float depot = (best == 0) ? 1.f : 0.f;
        if (cntv >= NN - 1) depot = 0.f;
        const float lg_b = __shfl(lgv, best);
        lpacc += (lg_b - mm) - logf(ee);
        if (l < NN) {
          mask_l = (l == 0) ? depot
                 : fminf((float)m1 + ((dem_l > dynr) ? 1.f : 0.f), 1.f);
          maskL[l] = mask_l;
        }
        qL[l]      = EQsh[best * RS + l]      + dynr * wr0 + qp0;
        qL[l + 64] = EQsh[best * RS + l + 64] + dynr * wr1 + qp1;
        if (l == 0) out[b * ns + t] = (float)best;
        pg = pgn;
      } else if (w == 3 && !greedy) {
        if (l < NN && t + 2 < ns)
          pgumL[t & 1][l] =
              gumbel_from(keysL[2 * (t + 2)], keysL[2 * (t + 2) + 1],
                          (unsigned)(b * NN + l));
      }
    }
    __syncthreads();
  }
  if (tid == 0) out[Bn * ns + b] = lpacc;
}

extern "C" void kernel_launch(void* const* d_in, const int* in_sizes, int n_in,
                              void* d_out, int out_size, void* d_ws, size_t ws_size,
                              hipStream_t stream) {
  const float* enc    = (const float*)d_in[0];
  const float* pool   = (const float*)d_in[1];
  const float* cap    = (const float*)d_in[2];
  const float* dem    = (const float*)d_in[3];
  const float* fc_w   = (const float*)d_in[4];
  const float* fc1_w  = (const float*)d_in[5];
  const float* wq     = (const float*)d_in[6];
  const float* wk     = (const float*)d_in[7];
  const float* wv     = (const float*)d_in[8];
  const float* wo     = (const float*)d_in[9];
  const float* wkp    = (const float*)d_in[10];
  const float* Tp     = (const float*)d_in[11];
  const int*   nsp    = (const int*)d_in[12];
  const int*   greedy = (const int*)d_in[14];
  float* out = (float*)d_out;

  const int B = in_sizes[1] / DD;  // pool is (B,128)

  hipLaunchKernelGGL(decode_kernel, dim3(B), dim3(256), 0, stream,
                     enc, pool, cap, dem, fc_w, fc1_w, wq, wk, wv, wo, wkp,
                     Tp, nsp, greedy, out);
}

// Round 6
// 253.080 us; speedup vs baseline: 1.3324x; 1.3324x over previous
//
#include <hip/hip_runtime.h>

#define NN 51
#define NVR 52    // V rows padded (row 51 zero)
#define DD 128
#define RS 132    // LDS row stride (stride%32==4 -> b128 conflict-free)
#define NT 64

// JAX threefry2x32 (20 rounds), exact.
__device__ __forceinline__ void tf2x32(unsigned k0, unsigned k1, unsigned &x0, unsigned &x1) {
  const unsigned ks2 = k0 ^ k1 ^ 0x1BD11BDAu;
  const unsigned ka[5] = {k1, ks2, k0, k1, ks2};
  const unsigned kb[5] = {ks2 + 1u, k0 + 2u, k1 + 3u, ks2 + 4u, k0 + 5u};
  x0 += k0; x1 += k1;
#pragma unroll
  for (int g = 0; g < 5; ++g) {
    const int r0 = (g & 1) ? 17 : 13;
    const int r1 = (g & 1) ? 29 : 15;
    const int r2 = (g & 1) ? 16 : 26;
    const int r3 = (g & 1) ? 24 : 6;
    x0 += x1; x1 = (x1 << r0) | (x1 >> (32 - r0)); x1 ^= x0;
    x0 += x1; x1 = (x1 << r1) | (x1 >> (32 - r1)); x1 ^= x0;
    x0 += x1; x1 = (x1 << r2) | (x1 >> (32 - r2)); x1 ^= x0;
    x0 += x1; x1 = (x1 << r3) | (x1 >> (32 - r3)); x1 ^= x0;
    x0 += ka[g]; x1 += kb[g];
  }
}

__device__ __forceinline__ float gumbel_from(unsigned k0, unsigned k1, unsigned ctr) {
  unsigned x0 = 0u, x1 = ctr;
  tf2x32(k0, k1, x0, x1);
  const unsigned bits = x0 ^ x1;
  const float fl = __uint_as_float((bits >> 9) | 0x3f800000u) - 1.0f;
  const float TINY = 1.17549435e-38f;
  const float uu = fmaxf(TINY, fl + TINY);
  return -logf(-logf(uu));
}

__device__ __forceinline__ float dot4(const float4 a, const float4 b) {
  return a.x * b.x + a.y * b.y + a.z * b.z + a.w * b.w;
}

__global__ __launch_bounds__(512, 1) void decode_kernel(
    const float* __restrict__ enc, const float* __restrict__ pool_in,
    const float* __restrict__ cap_p, const float* __restrict__ demand,
    const float* __restrict__ fc_w, const float* __restrict__ fc1,
    const float* __restrict__ wq, const float* __restrict__ wk,
    const float* __restrict__ wv, const float* __restrict__ wo,
    const float* __restrict__ wkp, const float* __restrict__ T_p,
    const int* __restrict__ ns_p, const int* __restrict__ greedy_p,
    float* __restrict__ out) {
  __shared__ __align__(16) float Ksh[NN * RS];
  __shared__ __align__(16) float Vsh[NVR * RS];    // row 51 zero
  __shared__ __align__(16) float KP2sh[NN * RS];   // T2=E@wkp -> KP2=T2@wo^T
  __shared__ __align__(16) float EQsh[NN * RS];    // T1=E@fc_top -> EQ=T1@wq
  __shared__ __align__(16) float qpoolL[NT * DD];  // staged enc, then qpool[t]
  __shared__ __align__(16) float gL[DD];
  __shared__ __align__(16) float poolL[DD];
  __shared__ __align__(16) float wrowL[DD];
  __shared__ __align__(16) float partF[512];
  __shared__ __align__(16) float partQ[512];
  __shared__ float demL[NN];
  __shared__ float logitsL[NN], pertL[NN];
  __shared__ float pgumL[2][NN];
  __shared__ unsigned keysL[2 * NT];
  __shared__ unsigned long long sM1;
  __shared__ float dynS, depotS, lpW0s, lpW1s;
  __shared__ int bestS;

  const int b = blockIdx.x, tid = threadIdx.x;
  const int Bn = gridDim.x;
  const int w = tid >> 6, l = tid & 63;
  int ns = *ns_p; if (ns > NT) ns = NT;
  const int greedy = *greedy_p;
  const float Tval = *T_p;
  const float cap0 = *cap_p;
  const float NINF = -__builtin_inff();

  // ---- stage ----
  {
    const float4* src = (const float4*)(enc + (size_t)b * NN * DD);
    float4* dst = (float4*)qpoolL;
    for (int e = tid; e < NN * DD / 4; e += 512) dst[e] = src[e];
  }
  if (tid < 128) poolL[tid] = pool_in[b * DD + tid];
  if (tid < RS)  Vsh[51 * RS + tid] = 0.f;
  if (tid < NN)  demL[tid] = demand[b * NN + tid];
  if (tid < ns) {  // fold_in(key(1234),0), then partitionable split child t
    unsigned a0 = 0u, a1 = 0u;
    tf2x32(0u, 1234u, a0, a1);
    unsigned x0 = 0u, x1 = (unsigned)tid;
    tf2x32(a0, a1, x0, x1);
    keysL[2 * tid] = x0; keysL[2 * tid + 1] = x1;
  }
  if (tid == 0) { bestS = 0; dynS = cap0; depotS = 1.f; sM1 = 1ull; }
  __syncthreads();  // S1

  float dem_l = (l < NN) ? demL[l] : 0.f;  // all waves keep their node's demand

  // gumbel(0) for step 0 (lanes 448+)
  if (!greedy && tid >= 448) {
    const int gl = tid - 448;
    if (gl < NN)
      pgumL[0][gl] = gumbel_from(keysL[0], keysL[1], (unsigned)(b * NN + gl));
  }
  // wrow partials: wrow[c] = fc_w[128,:] @ wq[:,c], 4-way depth split
  {
    const int c = tid & 127, qd = tid >> 7;
    const float* fr = fc_w + 128 * DD;
    float s = 0.f;
    for (int j = qd * 32; j < qd * 32 + 32; ++j) s += fr[j] * wq[j * DD + c];
    partF[tid] = s;
  }
  __syncthreads();  // S2
  if (tid < 128)
    wrowL[tid] = partF[tid] + partF[tid + 128] + partF[tid + 256] + partF[tid + 384];

  const int g4 = tid >> 7, cc = tid & 127;
  const int n0 = g4 * 13, cnt13 = (g4 == 3) ? 12 : 13;

  // ---- phase A: K=E@wk, V=E@wv, T1=E@fc_top, T2=E@wkp ----
  {
    const float* Wm[4] = {wk, wv, fc_w, wkp};
    float* Om[4] = {Ksh, Vsh, EQsh, KP2sh};
#pragma unroll
    for (int m = 0; m < 4; ++m) {
      const float* W = Wm[m];
      float acc[13];
#pragma unroll
      for (int r = 0; r < 13; ++r) acc[r] = 0.f;
      for (int i = 0; i < DD; i += 4) {
        const float w0 = W[(i + 0) * DD + cc];
        const float w1 = W[(i + 1) * DD + cc];
        const float w2 = W[(i + 2) * DD + cc];
        const float w3 = W[(i + 3) * DD + cc];
#pragma unroll
        for (int r = 0; r < 13; ++r) {
          if (r < cnt13) {
            const float4 e4 = *(const float4*)&qpoolL[(n0 + r) * DD + i];
            acc[r] += e4.x * w0 + e4.y * w1 + e4.z * w2 + e4.w * w3;
          }
        }
      }
      float* O = Om[m];
#pragma unroll
      for (int r = 0; r < 13; ++r) if (r < cnt13) O[(n0 + r) * RS + cc] = acc[r];
    }
  }
  __syncthreads();  // S3

  // ---- B1: EQ = T1 @ wq in place ----
  {
    float acc[13];
#pragma unroll
    for (int r = 0; r < 13; ++r) acc[r] = 0.f;
    for (int i = 0; i < DD; i += 4) {
      const float w0 = wq[(i + 0) * DD + cc];
      const float w1 = wq[(i + 1) * DD + cc];
      const float w2 = wq[(i + 2) * DD + cc];
      const float w3 = wq[(i + 3) * DD + cc];
#pragma unroll
      for (int r = 0; r < 13; ++r) {
        if (r < cnt13) {
          const float4 e4 = *(const float4*)&EQsh[(n0 + r) * RS + i];
          acc[r] += e4.x * w0 + e4.y * w1 + e4.z * w2 + e4.w * w3;
        }
      }
    }
    __syncthreads();  // S4
#pragma unroll
    for (int r = 0; r < 13; ++r) if (r < cnt13) EQsh[(n0 + r) * RS + cc] = acc[r];
  }
  __syncthreads();  // S5

  // ---- B2: KP2 = T2 @ wo^T in place ----
  {
    float acc[13];
#pragma unroll
    for (int r = 0; r < 13; ++r) acc[r] = 0.f;
    for (int d = 0; d < DD; d += 4) {
      const float4 w4 = *(const float4*)&wo[cc * DD + d];
#pragma unroll
      for (int r = 0; r < 13; ++r) {
        if (r < cnt13) {
          const float4 t4 = *(const float4*)&KP2sh[(n0 + r) * RS + d];
          acc[r] += t4.x * w4.x + t4.y * w4.y + t4.z * w4.z + t4.w * w4.w;
        }
      }
    }
    __syncthreads();  // S6
#pragma unroll
    for (int r = 0; r < 13; ++r) if (r < cnt13) KP2sh[(n0 + r) * RS + cc] = acc[r];
  }
  __syncthreads();  // S7

  // ---- phase C: pool chain; qpool[t] = pool_{t+1} @ wq (4-way depth) ----
  {
    const int i0 = g4 * 32;
    float wf[32], wqr[32];
#pragma unroll
    for (int i = 0; i < 32; ++i) {
      wf[i]  = fc1[(i0 + i) * DD + cc];
      wqr[i] = wq[(i0 + i) * DD + cc];
    }
    float sf = 0.f;
#pragma unroll
    for (int i = 0; i < 32; ++i) sf += poolL[i0 + i] * wf[i];
    partF[tid] = sf;
    __syncthreads();
    if (tid < 128)
      poolL[tid] = partF[tid] + partF[tid + 128] + partF[tid + 256] + partF[tid + 384];
    __syncthreads();
    for (int t = 0; t < ns; ++t) {
      float sq = 0.f, sfn = 0.f;
#pragma unroll
      for (int i = 0; i < 32; ++i) {
        const float p = poolL[i0 + i];
        sq  += p * wqr[i];
        sfn += p * wf[i];
      }
      partQ[tid] = sq; partF[tid] = sfn;
      __syncthreads();
      if (tid < 128) {
        qpoolL[t * DD + tid] =
            partQ[tid] + partQ[tid + 128] + partQ[tid + 256] + partQ[tid + 384];
        if (t + 1 < ns)
          poolL[tid] = partF[tid] + partF[tid + 128] + partF[tid + 256] + partF[tid + 384];
      }
      __syncthreads();
    }
  }

  // ---- decode: 3 barriers/step ----
  int m1 = 0;              // wave0: visited bit for node l
  float dynr = cap0;       // wave0: running capacity
  float lpacc0 = 0.f;      // wave0 lane0: sum logits[best]
  float lpacc1 = 0.f;      // wave1 lane0: sum LSE

  for (int t = 0; t < ns; ++t) {
    // X: wave w = head w; lane l = node l. QK + softmax + PV, no LDS round-trip.
    {
      const int hbase = w * 16;
      const int best = bestS;
      const float dyn = dynS;
      const float dep = depotS;
      const unsigned long long M1 = sM1;
      const bool maskedl =
          (l == 0) ? (dep > 0.f)
          : (l < NN ? ((((M1 >> l) & 1ull) != 0ull) || (dem_l > dyn)) : true);
      // q for this head, on the fly (broadcast LDS reads)
      float4 qv0, qv1, qv2, qv3;
      {
        const float4* eq = (const float4*)&EQsh[best * RS + hbase];
        const float4* wr = (const float4*)&wrowL[hbase];
        const float4* qp = (const float4*)&qpoolL[t * DD + hbase];
        const float4 e0 = eq[0], e1 = eq[1], e2 = eq[2], e3 = eq[3];
        const float4 r0 = wr[0], r1 = wr[1], r2 = wr[2], r3 = wr[3];
        const float4 p0 = qp[0], p1 = qp[1], p2 = qp[2], p3 = qp[3];
        qv0.x = e0.x + dyn * r0.x + p0.x; qv0.y = e0.y + dyn * r0.y + p0.y;
        qv0.z = e0.z + dyn * r0.z + p0.z; qv0.w = e0.w + dyn * r0.w + p0.w;
        qv1.x = e1.x + dyn * r1.x + p1.x; qv1.y = e1.y + dyn * r1.y + p1.y;
        qv1.z = e1.z + dyn * r1.z + p1.z; qv1.w = e1.w + dyn * r1.w + p1.w;
        qv2.x = e2.x + dyn * r2.x + p2.x; qv2.y = e2.y + dyn * r2.y + p2.y;
        qv2.z = e2.z + dyn * r2.z + p2.z; qv2.w = e2.w + dyn * r2.w + p2.w;
        qv3.x = e3.x + dyn * r3.x + p3.x; qv3.y = e3.y + dyn * r3.y + p3.y;
        qv3.z = e3.z + dyn * r3.z + p3.z; qv3.w = e3.w + dyn * r3.w + p3.w;
      }
      float u1 = NINF;
      if (l < NN && !maskedl) {
        const float4* kr = (const float4*)&Ksh[l * RS + hbase];
        u1 = 0.25f * ((dot4(kr[0], qv0) + dot4(kr[1], qv1)) +
                      (dot4(kr[2], qv2) + dot4(kr[3], qv3)));
      }
      float mx = u1;
#pragma unroll
      for (int o = 32; o; o >>= 1) mx = fmaxf(mx, __shfl_xor(mx, o));
      const float e = (u1 > NINF) ? expf(u1 - mx) : 0.f;
      float S = e;
#pragma unroll
      for (int o = 32; o; o >>= 1) S += __shfl_xor(S, o);
      // PV: lane -> (res = n mod 4, dlo); a_n broadcast via variable shfl
      const int res = l >> 4, dlo = l & 15;
      float acc = 0.f;
#pragma unroll
      for (int jj = 0; jj < 13; ++jj) {
        const int n = 4 * jj + res;            // max 51 (row 51 of V is zero)
        const float an = __shfl(e, n);
        acc += an * Vsh[n * RS + hbase + dlo];
      }
      acc += __shfl_xor(acc, 16);
      acc += __shfl_xor(acc, 32);
      if (res == 0) gL[hbase + dlo] = acc / S;
    }
    __syncthreads();
    // Y: waves 0-6: comp/logits/pert per node (8-lane groups); wave 7: gumbel(t+1)
    {
      if (w < 7) {
        const int gn = tid >> 3, li = tid & 7;
        if (gn < NN) {
          const float4* kp = (const float4*)&KP2sh[gn * RS + li * 16];
          const float4* gg = (const float4*)&gL[li * 16];
          float p = (dot4(kp[0], gg[0]) + dot4(kp[1], gg[1])) +
                    (dot4(kp[2], gg[2]) + dot4(kp[3], gg[3]));
          p += __shfl_xor(p, 1, 8);
          p += __shfl_xor(p, 2, 8);
          p += __shfl_xor(p, 4, 8);
          if (li == 0) {
            const float comp = p * 0.08838834764831845f;  // 128^-0.5
            const float lg = (10.f * tanhf(comp)) / Tval;
            const bool maskedn =
                (gn == 0) ? (depotS > 0.f)
                          : ((((sM1 >> gn) & 1ull) != 0ull) || (demL[gn] > dynS));
            const float lgv = maskedn ? NINF : lg;
            logitsL[gn] = lgv;
            pertL[gn] = greedy ? lgv : (lgv + pgumL[t & 1][gn]);
          }
        }
      } else {
        if (!greedy && l < NN && t + 1 < ns)
          pgumL[(t + 1) & 1][l] =
              gumbel_from(keysL[2 * (t + 1)], keysL[2 * (t + 1) + 1],
                          (unsigned)(b * NN + l));
      }
    }
    __syncthreads();
    // Z: wave0 = argmax + state; wave1 = LSE (parallel)
    {
      if (w == 0) {
        const float pv = (l < NN) ? pertL[l] : NINF;
        float vmax = pv;
#pragma unroll
        for (int o = 32; o; o >>= 1) vmax = fmaxf(vmax, __shfl_xor(vmax, o));
        const unsigned long long Meq = __ballot(pv == vmax);
        const int best = __ffsll(Meq) - 1;     // first max = jnp.argmax tie-break
        if (l == best) m1 = 1;
        const unsigned long long M = __ballot(m1 != 0);
        const int cntv = (int)__popcll(M & ~1ull);
        const float dem_b = __shfl(dem_l, best);
        dynr = (best == 0) ? cap0 : (dynr - dem_b);
        float depot = (best == 0) ? 1.f : 0.f;
        if (cntv >= NN - 1) depot = 0.f;
        if (l == 0) {
          bestS = best; dynS = dynr; depotS = depot; sM1 = M;
          lpacc0 += logitsL[best];
          out[b * ns + t] = (float)best;
        }
      } else if (w == 1) {
        const float lv = (l < NN) ? logitsL[l] : NINF;
        float mm = lv;
#pragma unroll
        for (int o = 32; o; o >>= 1) mm = fmaxf(mm, __shfl_xor(mm, o));
        float ee = (lv > NINF) ? expf(lv - mm) : 0.f;
#pragma unroll
        for (int o = 32; o; o >>= 1) ee += __shfl_xor(ee, o);
        if (l == 0) lpacc1 += mm + logf(ee);
      }
    }
    __syncthreads();
  }
  if (tid == 0)  lpW0s = lpacc0;
  if (tid == 64) lpW1s = lpacc1;
  __syncthreads();
  if (tid == 0) out[Bn * ns + b] = lpW0s - lpW1s;
}

extern "C" void kernel_launch(void* const* d_in, const int* in_sizes, int n_in,
                              void* d_out, int out_size, void* d_ws, size_t ws_size,
                              hipStream_t stream) {
  const float* enc    = (const float*)d_in[0];
  const float* pool   = (const float*)d_in[1];
  const float* cap    = (const float*)d_in[2];
  const float* dem    = (const float*)d_in[3];
  const float* fc_w   = (const float*)d_in[4];
  const float* fc1_w  = (const float*)d_in[5];
  const float* wq     = (const float*)d_in[6];
  const float* wk     = (const float*)d_in[7];
  const float* wv     = (const float*)d_in[8];
  const float* wo     = (const float*)d_in[9];
  const float* wkp    = (const float*)d_in[10];
  const float* Tp     = (const float*)d_in[11];
  const int*   nsp    = (const int*)d_in[12];
  const int*   greedy = (const int*)d_in[14];
  float* out = (float*)d_out;

  const int B = in_sizes[1] / DD;  // pool is (B,128)

  hipLaunchKernelGGL(decode_kernel, dim3(B), dim3(512), 0, stream,
                     enc, pool, cap, dem, fc_w, fc1_w, wq, wk, wv, wo, wkp,
                     Tp, nsp, greedy, out);
}